// Round 3
// baseline (37366.833 us; speedup 1.0000x reference)
//
#include <hip/hip_runtime.h>
#include <math.h>

#define B 16
#define S 32
#define T 64
#define H2 512
#define Hf 256
#define F 128
#define A 128
#define V 32000
#define SW 1024
#define NSTEP 63
#define VP1 32001
#define NSLABS 252
#define NBLK 256
#define LEADER 254

__device__ __forceinline__ float frcp(float x){ return __builtin_amdgcn_rcpf(x); }
__device__ __forceinline__ float fsigm(float x){ return frcp(1.f + __expf(-x)); }
__device__ __forceinline__ float ftanh_(float x){
    float e = __expf(-2.f*fabsf(x));
    float t = (1.f - e)*frcp(1.f + e);
    return x >= 0.f ? t : -t;
}

// -------- grid barrier: arr[256] per-block gen slots + release flag --------
// Arrival: one sc1 store per block (concurrent). Leader polls all slots with
// 256 threads (concurrent loads). Release: single flag, polled with relaxed
// agent loads (no RMW anywhere on the hot path).
__device__ __forceinline__ void gbar(unsigned* arr, unsigned* release, unsigned gen){
    const int blk = blockIdx.x, tid = threadIdx.x;
    __syncthreads();
    if (blk == LEADER){
        if (tid == 0){
            __threadfence();   // write back this XCD's L2 (publishes our phase writes)
            __hip_atomic_store(&arr[LEADER], gen, __ATOMIC_RELAXED, __HIP_MEMORY_SCOPE_AGENT);
        }
        while (__hip_atomic_load(&arr[tid], __ATOMIC_RELAXED, __HIP_MEMORY_SCOPE_AGENT) < gen)
            __builtin_amdgcn_s_sleep(1);
        __syncthreads();
        if (tid == 0){
            __threadfence();   // order polls before release store; inv stale lines
            __hip_atomic_store(release, gen, __ATOMIC_RELAXED, __HIP_MEMORY_SCOPE_AGENT);
        }
        __syncthreads();       // leader waves proceed only after tid0's fence completed
    } else {
        if (tid == 0){
            __threadfence();   // write back our phase writes
            __hip_atomic_store(&arr[blk], gen, __ATOMIC_RELAXED, __HIP_MEMORY_SCOPE_AGENT);
            while (__hip_atomic_load(release, __ATOMIC_RELAXED, __HIP_MEMORY_SCOPE_AGENT) < gen)
                __builtin_amdgcn_s_sleep(1);
            __threadfence();   // invalidate L1/L2 so plain loads see producers' data
        }
        __syncthreads();
    }
}

// ---------------- init ----------------
__global__ __launch_bounds__(256) void k_init0(
    const float* __restrict__ state, const float* __restrict__ emb,
    const float* __restrict__ W_cc, const float* __restrict__ b_cc,
    const int* __restrict__ summary,
    float* __restrict__ xh_g, float* __restrict__ c_g, float* __restrict__ cov,
    float* __restrict__ loss, unsigned* __restrict__ bar)
{
    int blk = blockIdx.x, tid = threadIdx.x;
    if (blk < 16){
        int b = blk;
        for (int j = tid; j < H2; j += 256){
            xh_g[b*640 + F + j] = state[b*2*H2 + j];
            c_g[b*H2 + j]       = state[b*2*H2 + H2 + j];
        }
        int tok = summary[b*T + 0];
        if (tid < F){
            float acc = 0.f;
            for (int k = 0; k < F; ++k) acc += emb[(size_t)tok*F + k]*W_cc[(size_t)k*F + tid];
            xh_g[b*640 + tid] = acc + b_cc[tid];
        }
        if (tid == 0) loss[b] = 0.f;
    } else {
        int j = blk - 16;
        for (int i = tid; i < 1024; i += 256) cov[j*1024 + i] = 0.f;
        if (j == 0){
            for (int i = tid; i < 320; i += 256) bar[i] = 0u;   // arr[256] + release + pad
        }
    }
}

// ---------------- precompute ws_aT[b][a][n] ----------------
__global__ __launch_bounds__(256) void k_wsa(
    const float* __restrict__ ws, const float* __restrict__ W_a, const float* __restrict__ b_a,
    float* __restrict__ ws_aT)
{
    __shared__ float wss2[512][20];
    int b = blockIdx.x, nt = blockIdx.y, tid = threadIdx.x;
    int n0 = nt*16;
    const float* wsrc = ws + ((size_t)(b*SW + n0))*H2;
    for (int i = tid; i < 16*512; i += 256){
        int n_l = i >> 9, k = i & 511;
        wss2[k][n_l] = wsrc[i];
    }
    __syncthreads();
    int a = tid & 127, nh = tid >> 7;
    float acc[8];
    float ba = b_a[a];
    #pragma unroll
    for (int j = 0; j < 8; ++j) acc[j] = ba;
    for (int k = 0; k < H2; ++k){
        float wa = W_a[k*A + a];
        const float4 u0 = *(const float4*)&wss2[k][nh*8];
        const float4 u1 = *(const float4*)&wss2[k][nh*8 + 4];
        acc[0] += u0.x*wa; acc[1] += u0.y*wa; acc[2] += u0.z*wa; acc[3] += u0.w*wa;
        acc[4] += u1.x*wa; acc[5] += u1.y*wa; acc[6] += u1.z*wa; acc[7] += u1.w*wa;
    }
    float* dst = ws_aT + ((size_t)(b*A + a))*SW + n0 + nh*8;
    #pragma unroll
    for (int j = 0; j < 8; ++j) dst[j] = acc[j];
}

// ---------------- precompute Wf = W_rc @ W1_top, bf = b_rc @ W1_top + b1 ----------------
__global__ __launch_bounds__(256) void k_wf(
    const float* __restrict__ W_rc, const float* __restrict__ b_rc,
    const float* __restrict__ W1, const float* __restrict__ b1,
    float* __restrict__ Wf, float* __restrict__ bf)
{
    __shared__ float wrc[4][512];
    int j = blockIdx.x, tid = threadIdx.x;
    if (j < 256){
        for (int i = tid; i < 2048; i += 256){
            int kk = i >> 9, r = i & 511;
            wrc[kk][r] = W_rc[((size_t)(j*4 + kk))*H2 + r];
        }
        __syncthreads();
        float a0=0,a1=0,a2=0,a3=0;
        for (int r = 0; r < 512; ++r){
            float w1 = W1[(size_t)r*Hf + tid];
            a0 += wrc[0][r]*w1; a1 += wrc[1][r]*w1; a2 += wrc[2][r]*w1; a3 += wrc[3][r]*w1;
        }
        Wf[((size_t)(j*4+0))*Hf + tid] = a0;
        Wf[((size_t)(j*4+1))*Hf + tid] = a1;
        Wf[((size_t)(j*4+2))*Hf + tid] = a2;
        Wf[((size_t)(j*4+3))*Hf + tid] = a3;
    } else {
        float acc = b1[tid];
        for (int r = 0; r < 512; ++r) acc += b_rc[r]*W1[(size_t)r*Hf + tid];
        bf[tid] = acc;
    }
}

// ---------------- persistent time-loop kernel ----------------
__global__ __launch_bounds__(256) void k_persist(
    const float* __restrict__ ws,      const float* __restrict__ ss,
    const int*   __restrict__ text_length, const int* __restrict__ summary,
    const int*   __restrict__ sumlen,
    const float* __restrict__ emb,     const float* __restrict__ W_cc,
    const float* __restrict__ b_cc,    const float* __restrict__ Wx,
    const float* __restrict__ Wh,      const float* __restrict__ b_lstm,
    const float* __restrict__ W_a,     const float* __restrict__ v_a,
    const float* __restrict__ W1,      const float* __restrict__ W2,
    const float* __restrict__ b2,      const float* __restrict__ W_rc,
    const float* __restrict__ b_rc,
    const float* __restrict__ ws_aT,   const float* __restrict__ Wf,
    const float* __restrict__ bf,
    float* __restrict__ xh_g,  float* __restrict__ c_g,  float* __restrict__ out_g,
    float* __restrict__ ctx_g, float* __restrict__ cov,  float* __restrict__ scores,
    float* __restrict__ part,  float* __restrict__ hid,  float* __restrict__ m_s,
    float* __restrict__ s_s,   float* __restrict__ covloss_part,
    float* __restrict__ loss,  float* __restrict__ d_out,
    unsigned* __restrict__ bar)
{
    __shared__ float smem_f[11648];
    const int blk = blockIdx.x, tid = threadIdx.x;
    unsigned* arr = bar;
    unsigned* rel = bar + 256;
    unsigned gen = 0;

    for (int t = 0; t < NSTEP; ++t){
        // ======== Phase A: gates+cell (blocks 0..127) || Phase F(t-1) (block 255) ========
        if (blk < 128){
            float* xh = smem_f;                               // [16][648]
            float4* red4 = (float4*)(smem_f + 16*648);        // [256]
            const float* src = xh_g + (t & 1)*B*640;
            for (int i = tid; i < 16*160; i += 256){
                int b = i/160, k4 = i - b*160;
                ((float4*)(xh + b*648))[k4] = ((const float4*)(src + b*640))[k4];
            }
            __syncthreads();
            int hcl = tid & 3, b = (tid >> 2) & 15, kq = tid >> 6;
            int col = blk*4 + hcl;
            const float* xb = xh + b*648;
            float g0=0,g1=0,g2=0,g3=0;
            int k0 = kq*160, k1 = k0 + 160;
            int kxe = k1 < F ? k1 : F;
            for (int k = k0; k < kxe; ++k){
                float xv = xb[k];
                const float* wr = Wx + (size_t)k*2048 + col;
                g0 += xv*wr[0]; g1 += xv*wr[512]; g2 += xv*wr[1024]; g3 += xv*wr[1536];
            }
            for (int k = (k0 > F ? k0 : F); k < k1; ++k){
                float xv = xb[k];
                const float* wr = Wh + (size_t)(k - F)*2048 + col;
                g0 += xv*wr[0]; g1 += xv*wr[512]; g2 += xv*wr[1024]; g3 += xv*wr[1536];
            }
            red4[tid] = make_float4(g0,g1,g2,g3);
            __syncthreads();
            if (kq == 0){
                float4 r1 = red4[tid+64], r2 = red4[tid+128], r3 = red4[tid+192];
                g0 += r1.x + r2.x + r3.x;  g1 += r1.y + r2.y + r3.y;
                g2 += r1.z + r2.z + r3.z;  g3 += r1.w + r2.w + r3.w;
                float gi = g0 + b_lstm[col];
                float gf = g1 + b_lstm[512 + col];
                float gg = g2 + b_lstm[1024 + col];
                float go = g3 + b_lstm[1536 + col];
                float cold = c_g[b*H2 + col];
                float cn = fsigm(gf)*cold + fsigm(gi)*ftanh_(gg);
                float o  = fsigm(go)*ftanh_(cn);
                float valid = (sumlen[b] - t - 1 > 0) ? 1.f : 0.f;
                out_g[b*H2 + col] = o;
                c_g[b*H2 + col]   = cn*valid;
                xh_g[((t+1)&1)*B*640 + b*640 + F + col] = o*valid;
            }
        } else if (blk == 255 && t > 0){
            int tf = t - 1;
            int b = tid >> 4, g = tid & 15;
            float m = -1e30f;
            for (int j = g; j < NSLABS; j += 16) m = fmaxf(m, m_s[b*NSLABS + j]);
            for (int off = 8; off > 0; off >>= 1) m = fmaxf(m, __shfl_down(m, off, 16));
            m = __shfl(m, 0, 16);
            float sden = 0.f;
            for (int j = g; j < NSLABS; j += 16) sden += s_s[b*NSLABS + j]*__expf(m_s[b*NSLABS + j] - m);
            for (int off = 8; off > 0; off >>= 1) sden += __shfl_down(sden, off, 16);
            int tok = summary[b*T + tf + 1];
            int tgt = (tok == -1) ? V : tok;
            float d = 0.f;
            for (int r = g; r < Hf; r += 16) d += hid[b*Hf + r]*W2[(size_t)r*VP1 + tgt];
            for (int off = 8; off > 0; off >>= 1) d += __shfl_down(d, off, 16);
            float cl = covloss_part[b*16 + g];
            for (int off = 8; off > 0; off >>= 1) cl += __shfl_down(cl, off, 16);
            if (g == 0){
                float logit = d + b2[tgt];
                float logp = logit - m - __logf(sden);
                float valid = (sumlen[b] - tf - 1 > 0) ? 1.f : 0.f;
                loss[b] = loss[b] + valid*(-logp + cl);
            }
        }
        gen++; gbar(arr, rel, gen);

        // ======== Phase B: attention scores (b = blk>>4, 64 n per block) ========
        {
            float* outs = smem_f;           // 512
            float* wos  = smem_f + 512;     // 128
            float* wac  = smem_f + 640;     // 128
            float* vas  = smem_f + 768;     // 128
            float* redB = smem_f + 896;     // 256
            int b = blk >> 4, sl = blk & 15, n0 = sl*64;
            for (int i = tid; i < H2; i += 256) outs[i] = out_g[b*H2 + i];
            if (tid < 128){ wac[tid] = W_a[(size_t)(2*H2)*A + tid]; vas[tid] = v_a[tid]; }
            __syncthreads();
            int a = tid & 127, kh = tid >> 7;
            float acc = 0.f;
            for (int k = kh*256; k < kh*256 + 256; ++k) acc += outs[k]*W_a[(size_t)(H2 + k)*A + a];
            redB[tid] = acc;
            __syncthreads();
            if (kh == 0) wos[a] = redB[a] + redB[a + 128];
            __syncthreads();
            int nl = tid & 63, ah = tid >> 6;
            int n = n0 + nl;
            float cv = cov[b*SW + n];
            float sc = 0.f;
            const float* wp = ws_aT + (size_t)b*A*SW + n;
            for (int a2 = ah*32; a2 < ah*32 + 32; ++a2)
                sc += ftanh_(wp[(size_t)a2*SW] + wos[a2] + cv*wac[a2]) * vas[a2];
            __syncthreads();
            redB[tid] = sc;
            __syncthreads();
            if (ah == 0){
                float tot = redB[nl] + redB[64+nl] + redB[128+nl] + redB[192+nl];
                int sent = n >> 5, w = n & 31;
                scores[b*SW + n] = (w < text_length[b*S + sent]) ? tot : -1e9f;
            }
        }
        gen++; gbar(arr, rel, gen);

        // ======== Phase C: softmax + ctx4 partials + coverage/covloss ========
        {
            float* redC   = smem_f;         // 256
            float* attn_s = smem_f + 256;   // 64
            int b = blk >> 4, sl = blk & 15, n0 = sl*64;
            const float* sb = scores + b*SW;
            float s0 = sb[tid], s1 = sb[256 + tid], s2 = sb[512 + tid], s3 = sb[768 + tid];
            redC[tid] = fmaxf(fmaxf(s0, s1), fmaxf(s2, s3));
            __syncthreads();
            for (int off = 128; off > 0; off >>= 1){ if (tid < off) redC[tid] = fmaxf(redC[tid], redC[tid+off]); __syncthreads(); }
            float M = redC[0];
            __syncthreads();
            redC[tid] = __expf(s0 - M) + __expf(s1 - M) + __expf(s2 - M) + __expf(s3 - M);
            __syncthreads();
            for (int off = 128; off > 0; off >>= 1){ if (tid < off) redC[tid] += redC[tid+off]; __syncthreads(); }
            float invS = frcp(redC[0]);
            __syncthreads();
            if (tid < 64) attn_s[tid] = __expf(sb[n0 + tid] - M)*invS;
            __syncthreads();
            float a0 = 0.f, a1 = 0.f, as0 = 0.f, as1 = 0.f;
            const float* wsb = ws + ((size_t)(b*SW + n0))*H2;
            for (int nn = 0; nn < 64; ++nn){
                float at = attn_s[nn];
                if (nn < 32) as0 += at; else as1 += at;
                const float* wrow = wsb + (size_t)nn*H2;
                a0 += at*wrow[tid];
                a1 += at*wrow[tid + 256];
            }
            int sA = 2*sl, sB = 2*sl + 1;
            const float* ssA = ss + ((size_t)(b*S + sA))*H2;
            const float* ssB = ss + ((size_t)(b*S + sB))*H2;
            float* pp = part + ((size_t)(b*16 + sl))*1024;
            pp[tid]       = a0;
            pp[tid + 256] = a1;
            pp[tid + 512] = as0*ssA[tid]       + as1*ssB[tid];
            pp[tid + 768] = as0*ssA[tid + 256] + as1*ssB[tid + 256];
            float clp = 0.f;
            if (tid < 64){
                int n = n0 + tid;
                float at = attn_s[tid];
                float cv = cov[b*SW + n];
                clp = fminf(cv, at);
                float valid = (sumlen[b] - t - 1 > 0) ? 1.f : 0.f;
                cov[b*SW + n] = cv + at*valid;
            }
            __syncthreads();
            redC[tid] = (tid < 64) ? clp : 0.f;
            __syncthreads();
            for (int off = 32; off > 0; off >>= 1){ if (tid < off) redC[tid] += redC[tid+off]; __syncthreads(); }
            if (tid == 0) covloss_part[b*16 + sl] = redC[0];
        }
        gen++; gbar(arr, rel, gen);

        // ======== Phase D: ctx_new (blocks 0..63) | hid (blocks 64..95) ========
        if (blk < 64){
            float* c4   = smem_f;            // 1024
            float* redD = smem_f + 1024;     // 256
            int b = blk >> 2, q = blk & 3;
            for (int d = tid; d < 1024; d += 256){
                float a = 0.f;
                const float* pp = part + (size_t)b*16*1024 + d;
                #pragma unroll
                for (int s2 = 0; s2 < 16; ++s2) a += pp[s2*1024];
                c4[d] = a;
            }
            __syncthreads();
            int col = q*128 + (tid & 127), kh = tid >> 7;
            float acc = 0.f;
            for (int k = kh*512; k < kh*512 + 512; ++k)
                acc += c4[k]*W_rc[(size_t)k*H2 + col];
            redD[tid] = acc;
            __syncthreads();
            if (kh == 0){
                float v2 = acc + redD[tid + 128] + b_rc[col];
                float valid = (sumlen[b] - t - 1 > 0) ? 1.f : 0.f;
                ctx_g[b*H2 + col] = v2*valid;
            }
        } else if (blk < 96){
            float* c4    = smem_f;           // 1024
            float* outsD = smem_f + 1024;    // 512
            float* redD  = smem_f + 1536;    // 256
            int jj = blk - 64, b = jj >> 1, q2 = jj & 1;
            for (int d = tid; d < 1024; d += 256){
                float a = 0.f;
                const float* pp = part + (size_t)b*16*1024 + d;
                #pragma unroll
                for (int s2 = 0; s2 < 16; ++s2) a += pp[s2*1024];
                c4[d] = a;
            }
            for (int i = tid; i < H2; i += 256) outsD[i] = out_g[b*H2 + i];
            __syncthreads();
            int col = q2*128 + (tid & 127), kh = tid >> 7;
            float acc = 0.f;
            for (int k = kh*512; k < kh*512 + 512; ++k) acc += c4[k]*Wf[(size_t)k*Hf + col];
            for (int k = kh*256; k < kh*256 + 256; ++k) acc += outsD[k]*W1[(size_t)(H2 + k)*Hf + col];
            redD[tid] = acc;
            __syncthreads();
            if (kh == 0)
                hid[b*Hf + col] = fmaxf(acc + redD[tid + 128] + bf[col], 0.f);
        }
        gen++; gbar(arr, rel, gen);

        // ======== Phase E: vocab logits slabs (blocks 0..251) | x_{t+1} (252..255) ========
        if (blk < NSLABS){
            float* hs   = smem_f;            // [256][20] = 5120
            float* redE = smem_f + 5120;     // [16][68] = 1088
            float* mrow = smem_f + 6208;     // 16
            float* Mrun = smem_f + 6224;     // 16
            float* Srun = smem_f + 6240;     // 16
            int v_base = blk*128;
            for (int i = tid; i < B*Hf; i += 256){ int b = i >> 8, r = i & 255; hs[r*20 + b] = hid[i]; }
            if (tid < 16){ Mrun[tid] = -1e30f; Srun[tid] = 0.f; }
            __syncthreads();
            int c = tid & 63, bq = tid >> 6;
            for (int chunk = 0; chunk < 2; ++chunk){
                int v = v_base + chunk*64 + c;
                bool ok = v < VP1;
                float acc0=0.f, acc1=0.f, acc2=0.f, acc3=0.f;
                if (ok){
                    const float* w2p = W2 + v;
                    for (int r = 0; r < Hf; ++r){
                        float w = w2p[(size_t)r*VP1];
                        const float4 h4 = *(const float4*)&hs[r*20 + bq*4];
                        acc0 += h4.x*w; acc1 += h4.y*w; acc2 += h4.z*w; acc3 += h4.w*w;
                    }
                    float bb = b2[v];
                    acc0 += bb; acc1 += bb; acc2 += bb; acc3 += bb;
                }
                redE[(bq*4+0)*68 + c] = ok ? acc0 : -1e30f;
                redE[(bq*4+1)*68 + c] = ok ? acc1 : -1e30f;
                redE[(bq*4+2)*68 + c] = ok ? acc2 : -1e30f;
                redE[(bq*4+3)*68 + c] = ok ? acc3 : -1e30f;
                __syncthreads();
                if (tid < 16){
                    float m = -1e30f;
                    for (int i = 0; i < 64; ++i) m = fmaxf(m, redE[tid*68 + i]);
                    mrow[tid] = m;
                }
                __syncthreads();
                float m0 = mrow[bq*4+0], m1 = mrow[bq*4+1], m2 = mrow[bq*4+2], m3 = mrow[bq*4+3];
                redE[(bq*4+0)*68 + c] = ok ? __expf(acc0 - m0) : 0.f;
                redE[(bq*4+1)*68 + c] = ok ? __expf(acc1 - m1) : 0.f;
                redE[(bq*4+2)*68 + c] = ok ? __expf(acc2 - m2) : 0.f;
                redE[(bq*4+3)*68 + c] = ok ? __expf(acc3 - m3) : 0.f;
                __syncthreads();
                if (tid < 16){
                    float ssum = 0.f;
                    for (int i = 0; i < 64; ++i) ssum += redE[tid*68 + i];
                    float cm = mrow[tid];
                    float Mo = Mrun[tid], So = Srun[tid];
                    float Mn = fmaxf(Mo, cm);
                    Srun[tid] = So*__expf(Mo - Mn) + ssum*__expf(cm - Mn);
                    Mrun[tid] = Mn;
                }
                __syncthreads();
            }
            if (tid < 16){
                m_s[tid*NSLABS + blk] = Mrun[tid];
                s_s[tid*NSLABS + blk] = Srun[tid];
            }
        } else {
            // x_{t+1} = [emb[tok_{t+1}], ctx_g] @ W_cc + b_cc   (blocks 252..255, 4 b each)
            float* ec   = smem_f;            // 640
            float* redX = smem_f + 640;      // 256
            int bs = (blk - NSLABS)*4;
            for (int bl = 0; bl < 4; ++bl){
                int b = bs + bl;
                int tok = summary[b*T + t + 1];
                for (int i = tid; i < 640; i += 256)
                    ec[i] = (i < F) ? emb[(size_t)tok*F + i] : ctx_g[b*H2 + (i - F)];
                __syncthreads();
                int f = tid & 127, kh = tid >> 7;
                float acc = 0.f;
                for (int k = kh*320; k < kh*320 + 320; ++k) acc += ec[k]*W_cc[(size_t)k*F + f];
                redX[tid] = acc;
                __syncthreads();
                if (kh == 0) xh_g[((t+1)&1)*B*640 + b*640 + f] = acc + redX[tid + 128] + b_cc[f];
                __syncthreads();
            }
        }
        gen++; gbar(arr, rel, gen);
    }

    // ======== tail: Phase F for t = NSTEP-1 (block 255) ========
    if (blk == 255){
        int tf = NSTEP - 1;
        int b = tid >> 4, g = tid & 15;
        float m = -1e30f;
        for (int j = g; j < NSLABS; j += 16) m = fmaxf(m, m_s[b*NSLABS + j]);
        for (int off = 8; off > 0; off >>= 1) m = fmaxf(m, __shfl_down(m, off, 16));
        m = __shfl(m, 0, 16);
        float sden = 0.f;
        for (int j = g; j < NSLABS; j += 16) sden += s_s[b*NSLABS + j]*__expf(m_s[b*NSLABS + j] - m);
        for (int off = 8; off > 0; off >>= 1) sden += __shfl_down(sden, off, 16);
        int tok = summary[b*T + tf + 1];
        int tgt = (tok == -1) ? V : tok;
        float d = 0.f;
        for (int r = g; r < Hf; r += 16) d += hid[b*Hf + r]*W2[(size_t)r*VP1 + tgt];
        for (int off = 8; off > 0; off >>= 1) d += __shfl_down(d, off, 16);
        float cl = covloss_part[b*16 + g];
        for (int off = 8; off > 0; off >>= 1) cl += __shfl_down(cl, off, 16);
        if (g == 0){
            float logit = d + b2[tgt];
            float logp = logit - m - __logf(sden);
            float valid = (sumlen[b] - tf - 1 > 0) ? 1.f : 0.f;
            float L = loss[b] + valid*(-logp + cl);
            d_out[b] = L / ((float)sumlen[b] - 1.f);
        }
    }
}

extern "C" void kernel_launch(void* const* d_in, const int* in_sizes, int n_in,
                              void* d_out, int out_size, void* d_ws, size_t ws_size,
                              hipStream_t stream) {
    const float* text_states = (const float*)d_in[0];
    const float* sent_states = (const float*)d_in[1];
    const int*   text_length = (const int*)d_in[2];
    const float* state       = (const float*)d_in[3];
    const int*   summary     = (const int*)d_in[4];
    const int*   sumlen      = (const int*)d_in[5];
    const float* emb    = (const float*)d_in[6];
    const float* W_cc   = (const float*)d_in[7];
    const float* b_cc   = (const float*)d_in[8];
    const float* Wx     = (const float*)d_in[9];
    const float* Wh     = (const float*)d_in[10];
    const float* b_lstm = (const float*)d_in[11];
    const float* W_a    = (const float*)d_in[12];
    const float* b_a    = (const float*)d_in[13];
    const float* v_a    = (const float*)d_in[14];
    const float* W_rc   = (const float*)d_in[15];
    const float* b_rc   = (const float*)d_in[16];
    const float* W1     = (const float*)d_in[17];
    const float* b1     = (const float*)d_in[18];
    const float* W2     = (const float*)d_in[19];
    const float* b2     = (const float*)d_in[20];
    float* out = (float*)d_out;

    float* p = (float*)d_ws;
    float* ws_aT     = p; p += (size_t)B*A*SW;      // 2,097,152
    float* Wf        = p; p += (size_t)1024*Hf;     // 262,144
    float* bf        = p; p += Hf;                  // 256
    float* xh_g      = p; p += 2*B*640;             // 20,480
    float* c_g       = p; p += B*H2;
    float* out_g     = p; p += B*H2;
    float* ctx_g     = p; p += B*H2;
    float* cov       = p; p += B*SW;
    float* scores    = p; p += B*SW;
    float* part      = p; p += (size_t)B*16*1024;   // 262,144
    float* hid       = p; p += B*Hf;
    float* m_s       = p; p += B*NSLABS;
    float* s_s       = p; p += B*NSLABS;
    float* covloss_p = p; p += B*16;
    float* loss      = p; p += B;
    unsigned* bar    = (unsigned*)p; p += 320;

    k_init0<<<32, 256, 0, stream>>>(state, emb, W_cc, b_cc, summary, xh_g, c_g, cov, loss, bar);
    k_wsa<<<dim3(B, 64), 256, 0, stream>>>(text_states, W_a, b_a, ws_aT);
    k_wf<<<257, 256, 0, stream>>>(W_rc, b_rc, W1, b1, Wf, bf);
    k_persist<<<NBLK, 256, 0, stream>>>(
        text_states, sent_states, text_length, summary, sumlen,
        emb, W_cc, b_cc, Wx, Wh, b_lstm, W_a, v_a, W1, W2, b2, W_rc, b_rc,
        ws_aT, Wf, bf,
        xh_g, c_g, out_g, ctx_g, cov, scores, part, hid, m_s, s_s,
        covloss_p, loss, out, bar);
}

// Round 5
// 8536.826 us; speedup vs baseline: 4.3771x; 4.3771x over previous
//
#include <hip/hip_runtime.h>
#include <math.h>

#define B 16
#define S 32
#define T 64
#define H2 512
#define Hf 256
#define F 128
#define A 128
#define V 32000
#define SW 1024
#define NSTEP 63
#define VP1 32001
#define NBLK 256

__device__ __forceinline__ float frcp(float x){ return __builtin_amdgcn_rcpf(x); }
__device__ __forceinline__ float fsigm(float x){ return frcp(1.f + __expf(-x)); }
__device__ __forceinline__ float ftanh_(float x){
    float e = __expf(-2.f*fabsf(x));
    float t = (1.f - e)*frcp(1.f + e);
    return x >= 0.f ? t : -t;
}
__device__ __forceinline__ float ald(const float* p){
    return __hip_atomic_load(p, __ATOMIC_RELAXED, __HIP_MEMORY_SCOPE_AGENT);
}
__device__ __forceinline__ void ast(float* p, float v){
    __hip_atomic_store(p, v, __ATOMIC_RELAXED, __HIP_MEMORY_SCOPE_AGENT);
}

// grid barrier: 8 striped counters, no fences (comm data is all agent-scope
// atomics; waitcnt at barrier entry drains each wave's stores before arrival).
__device__ __forceinline__ void gbar(unsigned* cnt, unsigned gen){
    asm volatile("s_waitcnt vmcnt(0) lgkmcnt(0)" ::: "memory");
    __syncthreads();
    if (threadIdx.x == 0)
        __hip_atomic_fetch_add(&cnt[(blockIdx.x & 7)*32], 1u,
                               __ATOMIC_RELAXED, __HIP_MEMORY_SCOPE_AGENT);
    if (threadIdx.x < 8){
        unsigned want = gen*32u;
        while (__hip_atomic_load(&cnt[threadIdx.x*32], __ATOMIC_RELAXED,
                                 __HIP_MEMORY_SCOPE_AGENT) < want)
            __builtin_amdgcn_s_sleep(4);
    }
    __syncthreads();
}

// ---------------- init ----------------
__global__ __launch_bounds__(256) void k_init0(
    const float* __restrict__ state, const float* __restrict__ emb,
    const float* __restrict__ W_cc, const float* __restrict__ b_cc,
    const int* __restrict__ summary,
    float* __restrict__ x_g, float* __restrict__ out_g,
    float* __restrict__ cov_g, unsigned* __restrict__ cnt)
{
    int blk = blockIdx.x, tid = threadIdx.x;
    if (blk < 16){
        int b = blk;
        for (int j = tid; j < H2; j += 256)
            out_g[B*H2 + b*H2 + j] = state[b*2*H2 + j];   // h into buffer 1
        int tok = summary[b*T + 0];
        if (tid < F){
            float a = 0.f;
            for (int k = 0; k < F; ++k) a += emb[(size_t)tok*F + k]*W_cc[(size_t)k*F + tid];
            x_g[b*F + tid] = a + b_cc[tid];
        }
    } else {
        int j = blk - 16;
        for (int i = tid; i < 1024; i += 256) cov_g[j*1024 + i] = 0.f;
        if (j == 0 && tid < 256) cnt[tid] = 0u;
    }
}

// ---------------- precompute ws_aT[b][a][n] ----------------
__global__ __launch_bounds__(256) void k_wsa(
    const float* __restrict__ ws, const float* __restrict__ W_a, const float* __restrict__ b_a,
    float* __restrict__ ws_aT)
{
    __shared__ float wss2[512][20];
    int b = blockIdx.x, nt = blockIdx.y, tid = threadIdx.x;
    int n0 = nt*16;
    const float* wsrc = ws + ((size_t)(b*SW + n0))*H2;
    for (int i = tid; i < 16*512; i += 256){
        int n_l = i >> 9, k = i & 511;
        wss2[k][n_l] = wsrc[i];
    }
    __syncthreads();
    int a = tid & 127, nh = tid >> 7;
    float acc[8];
    float ba = b_a[a];
    #pragma unroll
    for (int j = 0; j < 8; ++j) acc[j] = ba;
    for (int k = 0; k < H2; ++k){
        float wa = W_a[k*A + a];
        const float4 u0 = *(const float4*)&wss2[k][nh*8];
        const float4 u1 = *(const float4*)&wss2[k][nh*8 + 4];
        acc[0] += u0.x*wa; acc[1] += u0.y*wa; acc[2] += u0.z*wa; acc[3] += u0.w*wa;
        acc[4] += u1.x*wa; acc[5] += u1.y*wa; acc[6] += u1.z*wa; acc[7] += u1.w*wa;
    }
    float* dst = ws_aT + ((size_t)(b*A + a))*SW + n0 + nh*8;
    #pragma unroll
    for (int j = 0; j < 8; ++j) dst[j] = acc[j];
}

// ---------------- Wf = W_rc @ W1_top ; bf = b_rc@W1_top + b1 ; bconst = b_rc@W_cc_bot ----
__global__ __launch_bounds__(256) void k_wf(
    const float* __restrict__ W_rc, const float* __restrict__ b_rc,
    const float* __restrict__ W1, const float* __restrict__ b1,
    const float* __restrict__ W_cc,
    float* __restrict__ Wf, float* __restrict__ bf, float* __restrict__ bconst)
{
    __shared__ float wrc[4][512];
    int j = blockIdx.x, tid = threadIdx.x;
    if (j < 256){
        for (int i = tid; i < 2048; i += 256){
            int kk = i >> 9, r = i & 511;
            wrc[kk][r] = W_rc[((size_t)(j*4 + kk))*H2 + r];
        }
        __syncthreads();
        float a0=0,a1=0,a2=0,a3=0;
        for (int r = 0; r < 512; ++r){
            float w1 = W1[(size_t)r*Hf + tid];
            a0 += wrc[0][r]*w1; a1 += wrc[1][r]*w1; a2 += wrc[2][r]*w1; a3 += wrc[3][r]*w1;
        }
        Wf[((size_t)(j*4+0))*Hf + tid] = a0;
        Wf[((size_t)(j*4+1))*Hf + tid] = a1;
        Wf[((size_t)(j*4+2))*Hf + tid] = a2;
        Wf[((size_t)(j*4+3))*Hf + tid] = a3;
    } else {
        float acc = b1[tid];
        for (int r = 0; r < 512; ++r) acc += b_rc[r]*W1[(size_t)r*Hf + tid];
        bf[tid] = acc;
        if (tid < 128){
            float a = 0.f;
            for (int c = 0; c < H2; ++c) a += b_rc[c]*W_cc[(size_t)(F+c)*F + tid];
            bconst[tid] = a;
        }
    }
}

// ---------------- WRCC = W_rc @ W_cc_bot ----------------
__global__ __launch_bounds__(128) void k_wrcc(
    const float* __restrict__ W_rc, const float* __restrict__ W_cc, float* __restrict__ WRCC)
{
    __shared__ float wr[512];
    int d = blockIdx.x, f = threadIdx.x;
    for (int i = f; i < 512; i += 128) wr[i] = W_rc[(size_t)d*H2 + i];
    __syncthreads();
    float a = 0.f;
    for (int c = 0; c < H2; ++c) a += wr[c]*W_cc[(size_t)(F+c)*F + f];
    WRCC[(size_t)d*F + f] = a;
}

// ---------------- embx[t][b] = emb[tok_t]@W_cc_top + b_cc ----------------
__global__ __launch_bounds__(128) void k_embx(
    const int* __restrict__ summary, const float* __restrict__ emb,
    const float* __restrict__ W_cc, const float* __restrict__ b_cc,
    float* __restrict__ embx)
{
    __shared__ float er[128];
    int t = blockIdx.x, b = blockIdx.y, f = threadIdx.x;
    int tok = summary[b*T + t];
    er[f] = emb[(size_t)tok*F + f];
    __syncthreads();
    float a = b_cc[f];
    for (int k = 0; k < F; ++k) a += er[k]*W_cc[(size_t)k*F + f];
    embx[((size_t)t*B + b)*F + f] = a;
}

// ---------------- persistent time-loop kernel ----------------
__global__ __launch_bounds__(256, 1) void k_persist(
    const float* __restrict__ ws, const float* __restrict__ ss,
    const int* __restrict__ text_length, const int* __restrict__ summary,
    const int* __restrict__ sumlen, const float* __restrict__ state,
    const float* __restrict__ Wx, const float* __restrict__ Wh,
    const float* __restrict__ b_lstm, const float* __restrict__ W_a,
    const float* __restrict__ v_a, const float* __restrict__ W1,
    const float* __restrict__ W2, const float* __restrict__ b2,
    const float* __restrict__ ws_aT, const float* __restrict__ Wf,
    const float* __restrict__ bf, const float* __restrict__ WRCC,
    const float* __restrict__ bconst, const float* __restrict__ embx,
    float* out_g, float* x_g, float* hid_g, float* wo_g, float* w1bz,
    float* scores_g, float* mpart, float* spart, float* part,
    float* m2part, float* s2part, float* tgtlogit, float* covlp,
    float* cov_g, float* d_out, unsigned* cnt)
{
    __shared__ float L[10240];        // xh[16][640] | logit_l[128][16] | c4[1024]
    __shared__ float hid_l[4096];
    __shared__ float red_l[256];
    __shared__ float red2_l[256];
    __shared__ float gdot_l[128];
    __shared__ float wo_l[128];
    __shared__ float wac_l[128];
    __shared__ float vas_l[128];
    __shared__ float score_l[64];
    __shared__ float attn_l[64];
    __shared__ float cov_l[64];
    __shared__ float c_l[32];
    __shared__ float loss_l[16];
    __shared__ float misc[8];
    __shared__ int   tl_l[32];
    __shared__ int   sumlen_l[16];
    __shared__ int   tgt_l[16];

    const int blk = blockIdx.x, tid = threadIdx.x;

    // ---- resident weights (all statically indexed) ----
    float w2r[128]; float b2v;
    { int v = blk*128 + (tid>>1); int r0 = (tid&1)*128; bool ok = v < VP1;
      b2v = ok ? b2[v] : 0.f;
      #pragma unroll
      for (int i = 0; i < 128; ++i) w2r[i] = ok ? W2[(size_t)(r0+i)*VP1 + v] : 0.f; }
    float wsar[32];
    { int b3 = blk>>4; int n = (blk&15)*64 + (tid>>2); int a0 = (tid&3)*32;
      #pragma unroll
      for (int k = 0; k < 32; ++k) wsar[k] = ws_aT[((size_t)(b3*A + a0 + k))*SW + n]; }
    float wgr[20];
    { int cl = tid>>5, rc = tid&31; int col = (cl>>1)*512 + blk*2 + (cl&1);
      #pragma unroll
      for (int i = 0; i < 20; ++i){ int r = rc*20 + i;
        wgr[i] = (r < F) ? Wx[(size_t)r*(4*H2) + col] : Wh[(size_t)(r-F)*(4*H2) + col]; } }
    float wrole[64];
    if (blk < 128){
        int a = blk, rr = tid>>4;
        #pragma unroll
        for (int i = 0; i < 32; ++i) wrole[i] = W_a[(size_t)(H2 + rr*32 + i)*A + a];
        #pragma unroll
        for (int i = 32; i < 64; ++i) wrole[i] = 0.f;
    } else {
        int j = (blk-128)*2 + (tid>>7), rr = tid&7;
        #pragma unroll
        for (int i = 0; i < 64; ++i) wrole[i] = W1[(size_t)(H2 + rr*64 + i)*Hf + j];
    }
    // persistent LDS
    if (tid < 128){ wac_l[tid] = W_a[(size_t)(2*H2)*A + tid]; vas_l[tid] = v_a[tid]; }
    if (tid < 32) tl_l[tid] = text_length[(blk>>4)*S + tid];
    if (tid < 16){ sumlen_l[tid] = sumlen[tid]; loss_l[tid] = 0.f; }
    if (tid < 32){ int jl = tid>>4, b = tid&15;
        c_l[tid] = state[(size_t)b*2*H2 + H2 + blk*2 + jl]; }
    __syncthreads();

    unsigned gen = 0;
    for (int t = 0; t <= NSTEP; ++t){
        // ======== Phase I: gates(t) + W2-logits(t-1) ========
        if (t < NSTEP){
            #pragma unroll
            for (int k = 0; k < 8; ++k){ int i = k*256 + tid; int b = i>>7, f = i&127;
                L[b*640 + f] = ald(&x_g[i]); }
            const float* hsrc = out_g + ((t&1)^1)*(B*H2);
            #pragma unroll
            for (int k = 0; k < 32; ++k){ int i = k*256 + tid; int b = i>>9, r = i&511;
                float vp = (t==0) ? 1.f : ((sumlen_l[b] - t > 0) ? 1.f : 0.f);
                L[b*640 + F + r] = ald(&hsrc[i])*vp; }
        }
        if (t > 0){
            #pragma unroll
            for (int k = 0; k < 16; ++k){ int i = k*256 + tid; hid_l[i] = ald(&hid_g[i]); }
            if (tid < 16){ int tok = summary[tid*T + t]; tgt_l[tid] = (tok==-1)?V:tok; }
        }
        __syncthreads();
        if (t < NSTEP){
            int cl = tid>>5, rc = tid&31;
            #pragma unroll
            for (int b = 0; b < 16; ++b){
                float a = 0.f;
                const float* xb = &L[b*640 + rc*20];
                #pragma unroll
                for (int i = 0; i < 20; ++i) a = fmaf(xb[i], wgr[i], a);
                a += __shfl_down(a,16,32); a += __shfl_down(a,8,32);
                a += __shfl_down(a,4,32);  a += __shfl_down(a,2,32);
                a += __shfl_down(a,1,32);
                if (rc == 0) gdot_l[cl*16+b] = a;
            }
            __syncthreads();
            if (tid < 32){
                int jl = tid>>4, b = tid&15, col = blk*2 + jl;
                float gi = gdot_l[(jl)*16+b]   + b_lstm[col];
                float gf = gdot_l[(2+jl)*16+b] + b_lstm[H2+col];
                float gg = gdot_l[(4+jl)*16+b] + b_lstm[2*H2+col];
                float go = gdot_l[(6+jl)*16+b] + b_lstm[3*H2+col];
                float cold = c_l[tid];
                float cn = fsigm(gf)*cold + fsigm(gi)*ftanh_(gg);
                float o  = fsigm(go)*ftanh_(cn);
                float valid = (sumlen_l[b]-t-1 > 0) ? 1.f : 0.f;
                c_l[tid] = cn*valid;
                ast(&out_g[(t&1)*(B*H2) + b*H2 + col], o);
            }
        }
        if (t > 0){
            __syncthreads();              // xh dead -> reuse L as logit_l[128][16]
            float* logit_l = L;
            int v = blk*128 + (tid>>1), r0 = (tid&1)*128;
            bool ok = v < VP1;
            for (int b = 0; b < 16; ++b){
                const float4* h4 = (const float4*)&hid_l[b*256 + r0];
                float a = 0.f;
                #pragma unroll
                for (int i = 0; i < 32; ++i){ float4 h = h4[i];
                    a = fmaf(h.x, w2r[4*i],   a); a = fmaf(h.y, w2r[4*i+1], a);
                    a = fmaf(h.z, w2r[4*i+2], a); a = fmaf(h.w, w2r[4*i+3], a); }
                a += __shfl_xor(a, 1);
                if ((tid&1) == 0){
                    float lg = ok ? (a + b2v) : -1e30f;
                    logit_l[(tid>>1)*16 + b] = lg;
                    if (ok && v == tgt_l[b]) ast(&tgtlogit[b], lg);
                }
            }
            __syncthreads();
            int b = tid&15, cg = tid>>4;
            float m8 = -1e30f;
            #pragma unroll
            for (int i = 0; i < 8; ++i) m8 = fmaxf(m8, logit_l[(cg*8+i)*16 + b]);
            red2_l[b*16+cg] = m8;
            __syncthreads();
            if (tid < 16){ float m = -1e30f;
                for (int i = 0; i < 16; ++i) m = fmaxf(m, red2_l[tid*16+i]);
                red_l[tid] = m; }
            __syncthreads();
            float Mb = red_l[b];
            float s8 = 0.f;
            #pragma unroll
            for (int i = 0; i < 8; ++i) s8 += __expf(logit_l[(cg*8+i)*16+b] - Mb);
            red2_l[b*16+cg] = s8;
            __syncthreads();
            if (tid < 16){ float s = 0.f;
                for (int i = 0; i < 16; ++i) s += red2_l[tid*16+i];
                ast(&m2part[tid*256 + blk], red_l[tid]);
                ast(&s2part[tid*256 + blk], s); }
        }
        gen++; gbar(cnt, gen);

        // ======== Phase II: wo + w1b (t) ; loss-merge (t-1) ========
        if (t < NSTEP){
            const float* outc = out_g + (t&1)*(B*H2);
            if (blk < 128){
                int b = tid&15, rr = tid>>4;
                float a = 0.f;
                #pragma unroll
                for (int i = 0; i < 32; ++i) a = fmaf(ald(&outc[b*H2 + rr*32 + i]), wrole[i], a);
                red_l[rr*16 + b] = a;
                __syncthreads();
                if (tid < 16){ float s = 0.f;
                    #pragma unroll
                    for (int r = 0; r < 16; ++r) s += red_l[r*16 + tid];
                    ast(&wo_g[tid*128 + blk], s); }
            } else {
                int clw = tid>>7, b = (tid>>3)&15, rr = tid&7;
                float a = 0.f;
                #pragma unroll
                for (int i = 0; i < 64; ++i) a = fmaf(ald(&outc[b*H2 + rr*64 + i]), wrole[i], a);
                red_l[(clw*16 + b)*8 + rr] = a;
                __syncthreads();
                if (tid < 32){ int c2 = tid>>4, bb = tid&15; float s = 0.f;
                    #pragma unroll
                    for (int r = 0; r < 8; ++r) s += red_l[(c2*16+bb)*8 + r];
                    ast(&w1bz[bb*256 + (blk-128)*2 + c2], s); }
            }
        }
        if (t > 0 && blk == 255){
            __syncthreads();
            int tf = t-1, b = tid>>4, g = tid&15;
            float mv[16];
            #pragma unroll
            for (int i = 0; i < 16; ++i) mv[i] = ald(&m2part[b*256 + g*16 + i]);
            float M = -1e30f;
            #pragma unroll
            for (int i = 0; i < 16; ++i) M = fmaxf(M, mv[i]);
            #pragma unroll
            for (int off = 1; off < 16; off <<= 1) M = fmaxf(M, __shfl_xor(M, off, 16));
            float sden = 0.f;
            #pragma unroll
            for (int i = 0; i < 16; ++i)
                sden += ald(&s2part[b*256 + g*16 + i]) * __expf(mv[i] - M);
            #pragma unroll
            for (int off = 1; off < 16; off <<= 1) sden += __shfl_xor(sden, off, 16);
            if (g == 0){
                float tlg = ald(&tgtlogit[b]);
                float cl4 = ald(&covlp[b*4+0]) + ald(&covlp[b*4+1])
                          + ald(&covlp[b*4+2]) + ald(&covlp[b*4+3]);
                float logp = tlg - M - __logf(sden);
                float valid = (sumlen_l[b]-tf-1 > 0) ? 1.f : 0.f;
                loss_l[b] += valid*(-logp + cl4);
                if (t == NSTEP) d_out[b] = loss_l[b] / ((float)sumlen_l[b] - 1.f);
            }
        }
        if (t == NSTEP) break;
        gen++; gbar(cnt, gen);

        // ======== Phase III: attention scores ========
        {
            int b = blk>>4, sl = blk&15;
            if (tid < 128) wo_l[tid] = ald(&wo_g[b*128 + tid]);
            if (tid < 64)  cov_l[tid] = ald(&cov_g[b*SW + sl*64 + tid]);
            __syncthreads();
            int nl = tid>>2, ai = tid&3, a0 = ai*32;
            float cv = cov_l[nl];
            float acc = 0.f;
            #pragma unroll
            for (int k = 0; k < 32; ++k){
                float arg = wsar[k] + wo_l[a0+k] + cv*wac_l[a0+k];
                acc = fmaf(ftanh_(arg), vas_l[a0+k], acc);
            }
            acc += __shfl_xor(acc, 1);
            acc += __shfl_xor(acc, 2);
            if (ai == 0){
                int n = sl*64 + nl;
                float sc = ((n&31) < tl_l[n>>5]) ? acc : -1e9f;
                score_l[nl] = sc;
                ast(&scores_g[b*SW + n], sc);
            }
            __syncthreads();
            if (tid == 0){
                float m = score_l[0];
                for (int i = 1; i < 64; ++i) m = fmaxf(m, score_l[i]);
                float s = 0.f;
                for (int i = 0; i < 64; ++i) s += __expf(score_l[i]-m);
                ast(&mpart[b*16+sl], m);
                ast(&spart[b*16+sl], s);
            }
        }
        gen++; gbar(cnt, gen);

        // ======== Phase IV: attn + ctx4 partials ========
        {
            int b = blk>>4, sl = blk&15;
            if (tid < 16) red_l[tid] = ald(&mpart[b*16+tid]);
            else if (tid < 32) red_l[tid] = ald(&spart[b*16 + (tid-16)]);
            __syncthreads();
            if (tid == 0){
                float M = -1e30f;
                for (int i = 0; i < 16; ++i) M = fmaxf(M, red_l[i]);
                float Sv = 0.f;
                for (int i = 0; i < 16; ++i) Sv += red_l[16+i]*__expf(red_l[i]-M);
                misc[0] = M; misc[1] = frcp(Sv);
            }
            __syncthreads();
            if (tid < 64) attn_l[tid] = __expf(score_l[tid]-misc[0])*misc[1];
            __syncthreads();
            if (tid == 0){
                float a0s = 0.f, a1s = 0.f;
                for (int i = 0; i < 32; ++i) a0s += attn_l[i];
                for (int i = 32; i < 64; ++i) a1s += attn_l[i];
                misc[2] = a0s; misc[3] = a1s;
            }
            __syncthreads();
            const float* wsb = ws + ((size_t)(b*SW + sl*64))*H2;
            float p0 = 0.f, p1 = 0.f;
            #pragma unroll 4
            for (int nn = 0; nn < 64; ++nn){
                float a = attn_l[nn];
                p0 = fmaf(a, wsb[(size_t)nn*H2 + tid], p0);
                p1 = fmaf(a, wsb[(size_t)nn*H2 + 256 + tid], p1);
            }
            const float* ssA = ss + ((size_t)(b*S + 2*sl))*H2;
            float p2 = misc[2]*ssA[tid]       + misc[3]*ssA[H2 + tid];
            float p3 = misc[2]*ssA[256 + tid] + misc[3]*ssA[H2 + 256 + tid];
            size_t pb = ((size_t)(b*16 + sl))*1024;
            ast(&part[pb + tid], p0);
            ast(&part[pb + 256 + tid], p1);
            ast(&part[pb + 512 + tid], p2);
            ast(&part[pb + 768 + tid], p3);
        }
        gen++; gbar(cnt, gen);

        // ======== Phase V: hid / x / coverage ========
        {
            int b5 = blk>>4, r5 = blk&15;
            if (r5 < 12){
                float* c4 = L;
                #pragma unroll
                for (int q = 0; q < 4; ++q){
                    int d = q*256 + tid;
                    float s = 0.f;
                    #pragma unroll
                    for (int p = 0; p < 16; ++p)
                        s += ald(&part[((size_t)(b5*16+p))*1024 + d]);
                    c4[d] = s;
                }
                __syncthreads();
                int cl = tid&31, rh = tid>>5;
                if (r5 < 8){
                    int col = r5*32 + cl;
                    float a = 0.f;
                    const float* wp = Wf + (size_t)(rh*128)*Hf + col;
                    #pragma unroll 8
                    for (int i = 0; i < 128; ++i) a = fmaf(c4[rh*128+i], wp[(size_t)i*Hf], a);
                    red_l[cl*8 + rh] = a;
                    __syncthreads();
                    if (tid < 32){
                        float z = 0.f;
                        #pragma unroll
                        for (int r = 0; r < 8; ++r) z += red_l[tid*8+r];
                        z += ald(&w1bz[b5*256 + r5*32 + tid]) + bf[r5*32 + tid];
                        ast(&hid_g[b5*256 + r5*32 + tid], fmaxf(z, 0.f));
                    }
                } else {
                    int f = (r5-8)*32 + cl;
                    float a = 0.f;
                    const float* wp = WRCC + (size_t)(rh*128)*F + f;
                    #pragma unroll 8
                    for (int i = 0; i < 128; ++i) a = fmaf(c4[rh*128+i], wp[(size_t)i*F], a);
                    red_l[cl*8 + rh] = a;
                    __syncthreads();
                    if (tid < 32){
                        int f2 = (r5-8)*32 + tid;
                        float z = 0.f;
                        #pragma unroll
                        for (int r = 0; r < 8; ++r) z += red_l[tid*8+r];
                        float valid = (sumlen_l[b5]-t-1 > 0) ? 1.f : 0.f;
                        float xv = embx[((size_t)(t+1)*B + b5)*F + f2] + valid*(z + bconst[f2]);
                        ast(&x_g[b5*F + f2], xv);
                    }
                }
            } else {
                if (tid < 16) red_l[tid] = ald(&mpart[b5*16+tid]);
                else if (tid < 32) red_l[tid] = ald(&spart[b5*16 + tid-16]);
                __syncthreads();
                if (tid == 0){
                    float M = -1e30f;
                    for (int i = 0; i < 16; ++i) M = fmaxf(M, red_l[i]);
                    float Sv = 0.f;
                    for (int i = 0; i < 16; ++i) Sv += red_l[16+i]*__expf(red_l[i]-M);
                    misc[0] = M; misc[1] = frcp(Sv);
                }
                __syncthreads();
                int n = (r5-12)*256 + tid;
                float sc = ald(&scores_g[b5*SW + n]);
                float at = __expf(sc - misc[0])*misc[1];
                float cv = ald(&cov_g[b5*SW + n]);
                float valid = (sumlen_l[b5]-t-1 > 0) ? 1.f : 0.f;
                ast(&cov_g[b5*SW + n], cv + at*valid);
                red2_l[tid] = fminf(cv, at);
                __syncthreads();
                for (int off = 128; off > 0; off >>= 1){
                    if (tid < off) red2_l[tid] += red2_l[tid+off];
                    __syncthreads();
                }
                if (tid == 0) ast(&covlp[b5*4 + (r5-12)], red2_l[0]);
            }
        }
        gen++; gbar(cnt, gen);
    }
}

extern "C" void kernel_launch(void* const* d_in, const int* in_sizes, int n_in,
                              void* d_out, int out_size, void* d_ws, size_t ws_size,
                              hipStream_t stream) {
    const float* text_states = (const float*)d_in[0];
    const float* sent_states = (const float*)d_in[1];
    const int*   text_length = (const int*)d_in[2];
    const float* state       = (const float*)d_in[3];
    const int*   summary     = (const int*)d_in[4];
    const int*   sumlen      = (const int*)d_in[5];
    const float* emb    = (const float*)d_in[6];
    const float* W_cc   = (const float*)d_in[7];
    const float* b_cc   = (const float*)d_in[8];
    const float* Wx     = (const float*)d_in[9];
    const float* Wh     = (const float*)d_in[10];
    const float* b_lstm = (const float*)d_in[11];
    const float* W_a    = (const float*)d_in[12];
    const float* b_a    = (const float*)d_in[13];
    const float* v_a    = (const float*)d_in[14];
    const float* W_rc   = (const float*)d_in[15];
    const float* b_rc   = (const float*)d_in[16];
    const float* W1     = (const float*)d_in[17];
    const float* b1     = (const float*)d_in[18];
    const float* W2     = (const float*)d_in[19];
    const float* b2     = (const float*)d_in[20];
    float* out = (float*)d_out;

    float* p = (float*)d_ws;
    float* ws_aT    = p; p += (size_t)B*A*SW;      // 2,097,152
    float* Wf       = p; p += (size_t)1024*Hf;     // 262,144
    float* bfv      = p; p += Hf;
    float* WRCC     = p; p += (size_t)1024*F;      // 131,072
    float* bconst   = p; p += F;
    float* embx     = p; p += (size_t)T*B*F;       // 131,072
    float* out_g    = p; p += 2*B*H2;              // 16,384
    float* x_g      = p; p += B*F;
    float* hid_g    = p; p += B*Hf;
    float* wo_g     = p; p += B*A;
    float* w1bz     = p; p += B*Hf;
    float* scores_g = p; p += B*SW;
    float* mpart    = p; p += B*16;
    float* spart    = p; p += B*16;
    float* part     = p; p += (size_t)B*16*1024;   // 262,144
    float* m2part   = p; p += B*256;
    float* s2part   = p; p += B*256;
    float* tgtlog   = p; p += B;
    float* covlp    = p; p += B*4;
    float* cov_g    = p; p += B*SW;
    unsigned* cnt   = (unsigned*)p;

    k_init0<<<32, 256, 0, stream>>>(state, emb, W_cc, b_cc, summary, x_g, out_g, cov_g, cnt);
    k_wsa<<<dim3(B, 64), 256, 0, stream>>>(text_states, W_a, b_a, ws_aT);
    k_wf<<<257, 256, 0, stream>>>(W_rc, b_rc, W1, b1, W_cc, Wf, bfv, bconst);
    k_wrcc<<<1024, 128, 0, stream>>>(W_rc, W_cc, WRCC);
    k_embx<<<dim3(T, B), 128, 0, stream>>>(summary, emb, W_cc, b_cc, embx);
    k_persist<<<NBLK, 256, 0, stream>>>(
        text_states, sent_states, text_length, summary, sumlen, state,
        Wx, Wh, b_lstm, W_a, v_a, W1, W2, b2,
        ws_aT, Wf, bfv, WRCC, bconst, embx,
        out_g, x_g, hid_g, wo_g, w1bz, scores_g, mpart, spart, part,
        m2part, s2part, tgtlog, covlp, cov_g, out, cnt);
}